// Round 17
// baseline (146.594 us; speedup 1.0000x reference)
//
#include <hip/hip_runtime.h>

typedef __bf16 bf16x8 __attribute__((ext_vector_type(8)));
typedef short short8 __attribute__((ext_vector_type(8)));
typedef float f32x4 __attribute__((ext_vector_type(4)));

// B=8, T=2048, E=512, H=8, d=64
#define TT 2048
#define EE 512
#define NH 8
#define DD 64
#define NTERM 24

#define CSCALE 0.18033688011112042f   // 0.125 * log2(e)

__device__ __forceinline__ ushort f2bf(float f) {
  union { float f; unsigned u; } a; a.f = f;
  unsigned u = a.u;
  return (ushort)((u + 0x7FFFu + ((u >> 16) & 1u)) >> 16);  // RNE
}
__device__ __forceinline__ float bf2f(ushort b) {
  union { unsigned u; float f; } a; a.u = ((unsigned)b) << 16;
  return a.f;
}

// ---------------- Kernel 1: LayerNorm + q,k scalars (RAW) + xn (bf16) ------
// wave per token; 256 threads = 4 tokens/block; grid = 4096
__global__ __launch_bounds__(256) void k_ln(
    const float* __restrict__ x, const float* __restrict__ Wq,
    const float* __restrict__ Wk,
    float* __restrict__ Q, float* __restrict__ K, ushort* __restrict__ xnb) {
  const int token = blockIdx.x * 4 + (threadIdx.x >> 6);
  const int l = threadIdx.x & 63;
  const float* xr = x + (size_t)token * EE + l * 8;
  float4 a = *(const float4*)xr;
  float4 c = *(const float4*)(xr + 4);
  float xv[8] = {a.x, a.y, a.z, a.w, c.x, c.y, c.z, c.w};
  float s = 0.f, s2 = 0.f;
#pragma unroll
  for (int i = 0; i < 8; i++) { s += xv[i]; s2 = fmaf(xv[i], xv[i], s2); }
#pragma unroll
  for (int o = 32; o; o >>= 1) { s += __shfl_xor(s, o); s2 += __shfl_xor(s2, o); }
  const float mean = s * (1.f / 512.f);
  const float var = s2 * (1.f / 512.f) - mean * mean;
  const float rstd = rsqrtf(var + 1e-5f);

  float xn[8];
  short8 ob;
#pragma unroll
  for (int i = 0; i < 8; i++) {
    xn[i] = (xv[i] - mean) * rstd;
    ob[i] = (short)f2bf(xn[i]);
  }
  *(short8*)(xnb + (size_t)token * EE + l * 8) = ob;

  const float* wq = Wq + l * 8;
  const float* wk = Wk + l * 8;
  float4 q1 = *(const float4*)wq, q2 = *(const float4*)(wq + 4);
  float4 k1 = *(const float4*)wk, k2 = *(const float4*)(wk + 4);
  float wqv[8] = {q1.x, q1.y, q1.z, q1.w, q2.x, q2.y, q2.z, q2.w};
  float wkv[8] = {k1.x, k1.y, k1.z, k1.w, k2.x, k2.y, k2.z, k2.w};
  float q = 0.f, k = 0.f;
#pragma unroll
  for (int i = 0; i < 8; i++) { q = fmaf(xn[i], wqv[i], q); k = fmaf(xn[i], wkv[i], k); }
#pragma unroll
  for (int o = 4; o; o >>= 1) { q += __shfl_xor(q, o); k += __shfl_xor(k, o); }
  if ((l & 7) == 0) {
    const int h = l >> 3;
    const int b = token >> 11, t = token & (TT - 1);
    const int bh = b * NH + h;
    Q[bh * TT + t] = q;      // RAW (scaling folded into a_n/b_n)
    K[bh * TT + t] = k;
  }
}

// ---------------- Kernel 2: Wvmt[n][k] = (Wv_h @ Wm_h)^T, bf16 -------------
__global__ __launch_bounds__(256) void k_wvm(
    const float* __restrict__ Wv, const float* __restrict__ Wm,
    ushort* __restrict__ Wvmt) {
  const int k = blockIdx.x;
  const int h = k >> 6;
  const int tid = threadIdx.x;
  __shared__ float wv[64];
  if (tid < 64) wv[tid] = Wv[k * 64 + tid];
  __syncthreads();
  float a0 = 0.f, a1 = 0.f;
#pragma unroll 8
  for (int e = 0; e < 64; e++) {
    const float w = wv[e];
    const float* row = Wm + (size_t)(h * 64 + e) * EE;
    a0 = fmaf(w, row[tid], a0);
    a1 = fmaf(w, row[tid + 256], a1);
  }
  Wvmt[(size_t)tid * EE + k] = f2bf(a0);
  Wvmt[(size_t)(tid + 256) * EE + k] = f2bf(a1);
}

// ---------------- Kernel 3a: moments ----------------------------------------
// grid = 512: (bh = bx>>3, js = bx&7); 256 j's per block.
// M_n[e] = sum_j (k_j/2)^n exp(-k_j^2/8) xn_j[e],  m_n = sum_j (...)
// partials -> Mpart[bh][js][24][64], mpart[bh][js][24]
#define BSTR 257
__global__ __launch_bounds__(256) void k_mom(
    const float* __restrict__ K, const ushort* __restrict__ xnb,
    float* __restrict__ Mpart, float* __restrict__ mpart) {
  const int bx = blockIdx.x;
  const int bh = bx >> 3, js = bx & 7;
  const int b = bh >> 3, h = bh & 7;
  const int jbase = js * 256;
  const int tid = threadIdx.x;

  __shared__ ushort xs[256 * 64];        // 32 KB
  __shared__ float bcol[NTERM * BSTR];   // 24.7 KB

  // stage xn tile [256 j][64 e]
  {
    const ushort* src0 = xnb + (size_t)(b * TT + jbase) * EE + h * DD;
#pragma unroll
    for (int i = 0; i < 8; i++) {
      const int idx = i * 256 + tid;
      const int j = idx >> 3, ec = (idx & 7) * 8;
      *(uint4*)&xs[j * 64 + ec] = *(const uint4*)(src0 + (size_t)j * EE + ec);
    }
  }
  // stage b_n(k_j) columns
  {
    const float k = K[bh * TT + jbase + tid];
    const float e8 = __builtin_amdgcn_exp2f(-k * k * CSCALE);
    const float t = k * 0.5f;
    float bb = e8;
#pragma unroll
    for (int n = 0; n < NTERM; n++) {
      bcol[n * BSTR + tid] = bb;
      bb *= t;
    }
  }
  __syncthreads();

  if (tid < 192) {
    // cell: n = tid>>3 (0..23), eo = (tid&7)*8 (8 e's)
    const int n = tid >> 3;
    const int eo = (tid & 7) * 8;
    float acc[8] = {0.f, 0.f, 0.f, 0.f, 0.f, 0.f, 0.f, 0.f};
#pragma unroll 4
    for (int j = 0; j < 256; j++) {
      const float bv = bcol[n * BSTR + j];
      union { uint4 v; ushort u[8]; } xu;
      xu.v = *(const uint4*)&xs[j * 64 + eo];
#pragma unroll
      for (int i2 = 0; i2 < 8; i2++)
        acc[i2] = fmaf(bv, bf2f(xu.u[i2]), acc[i2]);
    }
    float* dst = Mpart + ((size_t)(bh * 8 + js) * NTERM + n) * 64 + eo;
#pragma unroll
    for (int i2 = 0; i2 < 8; i2++) dst[i2] = acc[i2];
  } else if (tid < 192 + NTERM) {
    const int n = tid - 192;
    float mm = 0.f;
    for (int j = 0; j < 256; j++) mm += bcol[n * BSTR + j];
    mpart[(size_t)(bh * 8 + js) * NTERM + n] = mm;
  }
}

// ---------------- Kernel 3b: per-query evaluation ---------------------------
// grid = 512: (bh = bx>>3, qc = bx&7); 4 waves x 64 queries; lane = e.
// O[e] = sum_n a_n(q) M_n[e], den = sum_n a_n m_n, a_n = (q/2)^n/n!
__global__ __launch_bounds__(256) void k_att2(
    const float* __restrict__ Q, const float* __restrict__ Mpart,
    const float* __restrict__ mpart, ushort* __restrict__ hr) {
  const int bx = blockIdx.x;
  const int bh = bx >> 3, qc = bx & 7;
  const int b = bh >> 3, h = bh & 7;
  const int tid = threadIdx.x;
  const int w = tid >> 6, l = tid & 63;

  // combine js-partials into registers (lane l holds column e = l)
  float Mreg[NTERM], mreg[NTERM];
#pragma unroll
  for (int n = 0; n < NTERM; n++) {
    float s = 0.f, sm = 0.f;
#pragma unroll
    for (int js = 0; js < 8; js++) {
      s += Mpart[((size_t)(bh * 8 + js) * NTERM + n) * 64 + l];
      sm += mpart[(size_t)(bh * 8 + js) * NTERM + n];
    }
    Mreg[n] = s; mreg[n] = sm;
  }

  static const float CINV[NTERM] = {
    1.f, 1.f, 1.f/2, 1.f/3, 1.f/4, 1.f/5, 1.f/6, 1.f/7, 1.f/8, 1.f/9,
    1.f/10, 1.f/11, 1.f/12, 1.f/13, 1.f/14, 1.f/15, 1.f/16, 1.f/17,
    1.f/18, 1.f/19, 1.f/20, 1.f/21, 1.f/22, 1.f/23};

  const int qbase = qc * 256 + w * 64;
#pragma unroll 2
  for (int qq = 0; qq < 64; qq++) {
    const int i = qbase + qq;
    const float q = Q[bh * TT + i];
    const float t = q * 0.5f;
    float a = 1.f;
    float acc = Mreg[0];
    float den = mreg[0];
#pragma unroll
    for (int n = 1; n < NTERM; n++) {
      a = a * t * CINV[n];
      acc = fmaf(a, Mreg[n], acc);
      den = fmaf(a, mreg[n], den);
    }
    const float r = acc * __builtin_amdgcn_rcpf(den);
    hr[(size_t)(b * TT + i) * EE + h * DD + l] = f2bf(r);
  }
}

// ---------------- Kernel 4: out = hr @ Wvm + x  (R11 verbatim) -------------
__global__ __launch_bounds__(256, 2) void k_merge(
    const ushort* __restrict__ hr, const ushort* __restrict__ Wmt,
    const float* __restrict__ x, float* __restrict__ out) {
  const int fid = blockIdx.y * 4 + blockIdx.x;   // dispatch order (x fastest)
  const int xcd = fid & 7, idx = fid >> 3;
  const int n0 = (idx & 3) * 128;
  const int m0 = (xcd * 16 + (idx >> 2)) * 128;
  const int tid = threadIdx.x;
  const int w = tid >> 6, l = tid & 63;
  const int l16 = l & 15, lhi = l >> 4;
  const int wm = w >> 1, wn = w & 1;

  __shared__ ushort As[2][128 * 72];
  __shared__ ushort Bs[2][128 * 72];
  f32x4 acc[4][4];
#pragma unroll
  for (int i = 0; i < 4; i++)
#pragma unroll
    for (int j = 0; j < 4; j++) acc[i][j] = (f32x4){0.f, 0.f, 0.f, 0.f};

  const int row = tid >> 1, half = tid & 1;
  const ushort* sa0 = hr + (size_t)(m0 + row) * EE + half * 32;
  const ushort* sb0 = Wmt + (size_t)(n0 + row) * EE + half * 32;

  {
    uint4* da = (uint4*)&As[0][row * 72 + half * 32];
    uint4* db = (uint4*)&Bs[0][row * 72 + half * 32];
#pragma unroll
    for (int i = 0; i < 4; i++) da[i] = *(const uint4*)(sa0 + i * 8);
#pragma unroll
    for (int i = 0; i < 4; i++) db[i] = *(const uint4*)(sb0 + i * 8);
  }
  __syncthreads();

  int p = 0;
  for (int k0 = 0; k0 < EE; k0 += 64) {
    const bool more = (k0 + 64) < EE;
    uint4 pa[4], pb[4];
    if (more) {
#pragma unroll
      for (int i = 0; i < 4; i++) pa[i] = *(const uint4*)(sa0 + k0 + 64 + i * 8);
#pragma unroll
      for (int i = 0; i < 4; i++) pb[i] = *(const uint4*)(sb0 + k0 + 64 + i * 8);
    }
#pragma unroll
    for (int kk = 0; kk < 2; kk++) {
      bf16x8 af[4], bfr[4];
#pragma unroll
      for (int mi = 0; mi < 4; mi++)
        af[mi] = *(const bf16x8*)&As[p][(wm * 64 + mi * 16 + l16) * 72 + kk * 32 + lhi * 8];
#pragma unroll
      for (int ni = 0; ni < 4; ni++)
        bfr[ni] = *(const bf16x8*)&Bs[p][(wn * 64 + ni * 16 + l16) * 72 + kk * 32 + lhi * 8];
#pragma unroll
      for (int mi = 0; mi < 4; mi++)
#pragma unroll
        for (int ni = 0; ni < 4; ni++)
          acc[mi][ni] = __builtin_amdgcn_mfma_f32_16x16x32_bf16(af[mi], bfr[ni], acc[mi][ni], 0, 0, 0);
    }
    if (more) {
      uint4* da = (uint4*)&As[p ^ 1][row * 72 + half * 32];
      uint4* db = (uint4*)&Bs[p ^ 1][row * 72 + half * 32];
#pragma unroll
      for (int i = 0; i < 4; i++) da[i] = pa[i];
#pragma unroll
      for (int i = 0; i < 4; i++) db[i] = pb[i];
    }
    __syncthreads();
    p ^= 1;
  }

#pragma unroll
  for (int mi = 0; mi < 4; mi++) {
#pragma unroll
    for (int r = 0; r < 4; r++) {
      const int grow = m0 + wm * 64 + mi * 16 + lhi * 4 + r;
#pragma unroll
      for (int ni = 0; ni < 4; ni++) {
        const int gcol = n0 + wn * 64 + ni * 16 + l16;
        size_t idx2 = (size_t)grow * EE + gcol;
        out[idx2] = acc[mi][ni][r] + x[idx2];
      }
    }
  }
}

// ---------------- launch ----------------------------------------------------
extern "C" void kernel_launch(void* const* d_in, const int* in_sizes, int n_in,
                              void* d_out, int out_size, void* d_ws, size_t ws_size,
                              hipStream_t stream) {
  const float* x  = (const float*)d_in[0];
  const float* Wq = (const float*)d_in[1];
  const float* Wk = (const float*)d_in[2];
  const float* Wv = (const float*)d_in[3];
  const float* Wm = (const float*)d_in[4];
  float* out = (float*)d_out;

  char* ws = (char*)d_ws;
  // layout (bytes):
  //   0        Q  f32 [64][2048]                (512 KB)
  //   524288   K  f32 [64][2048]                (512 KB)
  //   1048576  xnb bf16 [16384][512]            (16 MB)
  //   17825792 hr  bf16 [16384][512]            (16 MB)
  //   34603008 Mpart f32 [64][8][24][64]        (3.15 MB)
  //   37748736 mpart f32 [64][8][24]            (48 KB)
  //   37847040 Wvmt bf16 [512][512]             (512 KB)
  float*  Qp    = (float*)(ws);
  float*  Kp    = (float*)(ws + 524288);
  ushort* xnb   = (ushort*)(ws + 1048576);
  ushort* hrp   = (ushort*)(ws + 17825792);
  float*  Mpart = (float*)(ws + 34603008);
  float*  mpart = (float*)(ws + 37748736);
  ushort* Wvmt  = (ushort*)(ws + 37847040);

  k_ln<<<4096, 256, 0, stream>>>(x, Wq, Wk, Qp, Kp, xnb);
  k_wvm<<<EE, 256, 0, stream>>>(Wv, Wm, Wvmt);
  k_mom<<<512, 256, 0, stream>>>(Kp, xnb, Mpart, mpart);
  k_att2<<<512, 256, 0, stream>>>(Qp, Mpart, mpart, hrp);
  k_merge<<<dim3(EE / 128, (8 * TT) / 128), 256, 0, stream>>>(hrp, Wvmt, x, out);
}

// Round 18
// 103.037 us; speedup vs baseline: 1.4227x; 1.4227x over previous
//
#include <hip/hip_runtime.h>

typedef __bf16 bf16x8 __attribute__((ext_vector_type(8)));
typedef short short8 __attribute__((ext_vector_type(8)));
typedef float f32x4 __attribute__((ext_vector_type(4)));

// B=8, T=2048, E=512, H=8, d=64
#define TT 2048
#define EE 512
#define NH 8
#define DD 64
#define NTERM 24

#define CSCALE 0.18033688011112042f   // 0.125 * log2(e)

__device__ __forceinline__ ushort f2bf(float f) {
  union { float f; unsigned u; } a; a.f = f;
  unsigned u = a.u;
  return (ushort)((u + 0x7FFFu + ((u >> 16) & 1u)) >> 16);  // RNE
}
__device__ __forceinline__ float bf2f(ushort b) {
  union { unsigned u; float f; } a; a.u = ((unsigned)b) << 16;
  return a.f;
}

// ---------------- Kernel 1: LayerNorm + q,k scalars (RAW) + xn (bf16) ------
__global__ __launch_bounds__(256) void k_ln(
    const float* __restrict__ x, const float* __restrict__ Wq,
    const float* __restrict__ Wk,
    float* __restrict__ Q, float* __restrict__ K, ushort* __restrict__ xnb) {
  const int token = blockIdx.x * 4 + (threadIdx.x >> 6);
  const int l = threadIdx.x & 63;
  const float* xr = x + (size_t)token * EE + l * 8;
  float4 a = *(const float4*)xr;
  float4 c = *(const float4*)(xr + 4);
  float xv[8] = {a.x, a.y, a.z, a.w, c.x, c.y, c.z, c.w};
  float s = 0.f, s2 = 0.f;
#pragma unroll
  for (int i = 0; i < 8; i++) { s += xv[i]; s2 = fmaf(xv[i], xv[i], s2); }
#pragma unroll
  for (int o = 32; o; o >>= 1) { s += __shfl_xor(s, o); s2 += __shfl_xor(s2, o); }
  const float mean = s * (1.f / 512.f);
  const float var = s2 * (1.f / 512.f) - mean * mean;
  const float rstd = rsqrtf(var + 1e-5f);

  float xn[8];
  short8 ob;
#pragma unroll
  for (int i = 0; i < 8; i++) {
    xn[i] = (xv[i] - mean) * rstd;
    ob[i] = (short)f2bf(xn[i]);
  }
  *(short8*)(xnb + (size_t)token * EE + l * 8) = ob;

  const float* wq = Wq + l * 8;
  const float* wk = Wk + l * 8;
  float4 q1 = *(const float4*)wq, q2 = *(const float4*)(wq + 4);
  float4 k1 = *(const float4*)wk, k2 = *(const float4*)(wk + 4);
  float wqv[8] = {q1.x, q1.y, q1.z, q1.w, q2.x, q2.y, q2.z, q2.w};
  float wkv[8] = {k1.x, k1.y, k1.z, k1.w, k2.x, k2.y, k2.z, k2.w};
  float q = 0.f, k = 0.f;
#pragma unroll
  for (int i = 0; i < 8; i++) { q = fmaf(xn[i], wqv[i], q); k = fmaf(xn[i], wkv[i], k); }
#pragma unroll
  for (int o = 4; o; o >>= 1) { q += __shfl_xor(q, o); k += __shfl_xor(k, o); }
  if ((l & 7) == 0) {
    const int h = l >> 3;
    const int b = token >> 11, t = token & (TT - 1);
    const int bh = b * NH + h;
    Q[bh * TT + t] = q;      // RAW (scaling folded into moments)
    K[bh * TT + t] = k;
  }
}

// ---------------- Kernel 2: Wvmt[n][k] = (Wv_h @ Wm_h)^T, bf16 -------------
__global__ __launch_bounds__(256) void k_wvm(
    const float* __restrict__ Wv, const float* __restrict__ Wm,
    ushort* __restrict__ Wvmt) {
  const int k = blockIdx.x;
  const int h = k >> 6;
  const int tid = threadIdx.x;
  __shared__ float wv[64];
  if (tid < 64) wv[tid] = Wv[k * 64 + tid];
  __syncthreads();
  float a0 = 0.f, a1 = 0.f;
#pragma unroll 8
  for (int e = 0; e < 64; e++) {
    const float w = wv[e];
    const float* row = Wm + (size_t)(h * 64 + e) * EE;
    a0 = fmaf(w, row[tid], a0);
    a1 = fmaf(w, row[tid + 256], a1);
  }
  Wvmt[(size_t)tid * EE + k] = f2bf(a0);
  Wvmt[(size_t)(tid + 256) * EE + k] = f2bf(a1);
}

// ---------------- Kernel 3a: moments (unchanged) ----------------------------
#define BSTR 257
__global__ __launch_bounds__(256) void k_mom(
    const float* __restrict__ K, const ushort* __restrict__ xnb,
    float* __restrict__ Mpart, float* __restrict__ mpart) {
  const int bx = blockIdx.x;
  const int bh = bx >> 3, js = bx & 7;
  const int b = bh >> 3, h = bh & 7;
  const int jbase = js * 256;
  const int tid = threadIdx.x;

  __shared__ ushort xs[256 * 64];        // 32 KB
  __shared__ float bcol[NTERM * BSTR];   // 24.7 KB

  {
    const ushort* src0 = xnb + (size_t)(b * TT + jbase) * EE + h * DD;
#pragma unroll
    for (int i = 0; i < 8; i++) {
      const int idx = i * 256 + tid;
      const int j = idx >> 3, ec = (idx & 7) * 8;
      *(uint4*)&xs[j * 64 + ec] = *(const uint4*)(src0 + (size_t)j * EE + ec);
    }
  }
  {
    const float k = K[bh * TT + jbase + tid];
    const float e8 = __builtin_amdgcn_exp2f(-k * k * CSCALE);
    const float t = k * 0.5f;
    float bb = e8;
#pragma unroll
    for (int n = 0; n < NTERM; n++) {
      bcol[n * BSTR + tid] = bb;
      bb *= t;
    }
  }
  __syncthreads();

  if (tid < 192) {
    const int n = tid >> 3;
    const int eo = (tid & 7) * 8;
    float acc[8] = {0.f, 0.f, 0.f, 0.f, 0.f, 0.f, 0.f, 0.f};
#pragma unroll 4
    for (int j = 0; j < 256; j++) {
      const float bv = bcol[n * BSTR + j];
      union { uint4 v; ushort u[8]; } xu;
      xu.v = *(const uint4*)&xs[j * 64 + eo];
#pragma unroll
      for (int i2 = 0; i2 < 8; i2++)
        acc[i2] = fmaf(bv, bf2f(xu.u[i2]), acc[i2]);
    }
    float* dst = Mpart + ((size_t)(bh * 8 + js) * NTERM + n) * 64 + eo;
#pragma unroll
    for (int i2 = 0; i2 < 8; i2++) dst[i2] = acc[i2];
  } else if (tid < 192 + NTERM) {
    const int n = tid - 192;
    float mm = 0.f;
    for (int j = 0; j < 256; j++) mm += bcol[n * BSTR + j];
    mpart[(size_t)(bh * 8 + js) * NTERM + n] = mm;
  }
}

// ---------------- Kernel 3b: combine partials + fold 1/(2^n n!) ------------
// grid = 64 (bh); Mfull[bh][n][e] f32, mfull[bh][n] f32
__global__ __launch_bounds__(256) void k_cmb(
    const float* __restrict__ Mpart, const float* __restrict__ mpart,
    float* __restrict__ Mfull, float* __restrict__ mfull) {
  const int bh = blockIdx.x;
  const int tid = threadIdx.x;
  for (int idx = tid; idx < NTERM * 64; idx += 256) {
    const int n = idx >> 6, e = idx & 63;
    float s = 0.f;
#pragma unroll
    for (int js = 0; js < 8; js++)
      s += Mpart[((size_t)(bh * 8 + js) * NTERM + n) * 64 + e];
    float c = 1.f;
    for (int m2 = 1; m2 <= n; m2++) c /= (2.f * m2);
    Mfull[(size_t)(bh * NTERM + n) * 64 + e] = s * c;
  }
  if (tid < NTERM) {
    float s = 0.f;
#pragma unroll
    for (int js = 0; js < 8; js++)
      s += mpart[(size_t)(bh * 8 + js) * NTERM + tid];
    float c = 1.f;
    for (int m2 = 1; m2 <= tid; m2++) c /= (2.f * m2);
    mfull[bh * NTERM + tid] = s * c;
  }
}

// ---------------- Kernel 3c: per-query Horner evaluation --------------------
// grid = 1024: (bh = bx>>4, qc = bx&15); 4 waves x 32 queries; lane = e.
// acc = Horner_n(q; Mreg), den = Horner_n(q; mreg); hr = acc/den.
// launch_bounds(256,2): Mreg/mreg MUST stay in VGPRs (R17 lesson: default
// occupancy target spilled 48 floats to scratch -> 66 us).
__global__ __launch_bounds__(256, 2) void k_att2(
    const float* __restrict__ Q, const float* __restrict__ Mfull,
    const float* __restrict__ mfull, ushort* __restrict__ hr) {
  const int bx = blockIdx.x;
  const int bh = bx >> 4, qc = bx & 15;
  const int b = bh >> 3, h = bh & 7;
  const int tid = threadIdx.x;
  const int w = tid >> 6, l = tid & 63;

  float Mreg[NTERM], mreg[NTERM];
#pragma unroll
  for (int n = 0; n < NTERM; n++) {
    Mreg[n] = Mfull[(size_t)(bh * NTERM + n) * 64 + l];
    mreg[n] = mfull[bh * NTERM + n];
  }

  const int qbase = qc * 128 + w * 32;
  const float* Qb = Q + bh * TT + qbase;
  ushort* hb = hr + (size_t)(b * TT + qbase) * EE + h * DD + l;

#pragma unroll
  for (int qq = 0; qq < 32; qq += 4) {
    float qv[4], ac[4], dn[4];
#pragma unroll
    for (int u = 0; u < 4; u++) {
      qv[u] = Qb[qq + u];
      ac[u] = Mreg[NTERM - 1];
      dn[u] = mreg[NTERM - 1];
    }
#pragma unroll
    for (int n = NTERM - 2; n >= 0; n--) {
#pragma unroll
      for (int u = 0; u < 4; u++) {
        ac[u] = fmaf(ac[u], qv[u], Mreg[n]);
        dn[u] = fmaf(dn[u], qv[u], mreg[n]);
      }
    }
#pragma unroll
    for (int u = 0; u < 4; u++) {
      const float r = ac[u] * __builtin_amdgcn_rcpf(dn[u]);
      hb[(size_t)(qq + u) * EE] = f2bf(r);
    }
  }
}

// ---------------- Kernel 4: out = hr @ Wvm + x  (R11 verbatim) -------------
__global__ __launch_bounds__(256, 2) void k_merge(
    const ushort* __restrict__ hr, const ushort* __restrict__ Wmt,
    const float* __restrict__ x, float* __restrict__ out) {
  const int fid = blockIdx.y * 4 + blockIdx.x;   // dispatch order (x fastest)
  const int xcd = fid & 7, idx = fid >> 3;
  const int n0 = (idx & 3) * 128;
  const int m0 = (xcd * 16 + (idx >> 2)) * 128;
  const int tid = threadIdx.x;
  const int w = tid >> 6, l = tid & 63;
  const int l16 = l & 15, lhi = l >> 4;
  const int wm = w >> 1, wn = w & 1;

  __shared__ ushort As[2][128 * 72];
  __shared__ ushort Bs[2][128 * 72];
  f32x4 acc[4][4];
#pragma unroll
  for (int i = 0; i < 4; i++)
#pragma unroll
    for (int j = 0; j < 4; j++) acc[i][j] = (f32x4){0.f, 0.f, 0.f, 0.f};

  const int row = tid >> 1, half = tid & 1;
  const ushort* sa0 = hr + (size_t)(m0 + row) * EE + half * 32;
  const ushort* sb0 = Wmt + (size_t)(n0 + row) * EE + half * 32;

  {
    uint4* da = (uint4*)&As[0][row * 72 + half * 32];
    uint4* db = (uint4*)&Bs[0][row * 72 + half * 32];
#pragma unroll
    for (int i = 0; i < 4; i++) da[i] = *(const uint4*)(sa0 + i * 8);
#pragma unroll
    for (int i = 0; i < 4; i++) db[i] = *(const uint4*)(sb0 + i * 8);
  }
  __syncthreads();

  int p = 0;
  for (int k0 = 0; k0 < EE; k0 += 64) {
    const bool more = (k0 + 64) < EE;
    uint4 pa[4], pb[4];
    if (more) {
#pragma unroll
      for (int i = 0; i < 4; i++) pa[i] = *(const uint4*)(sa0 + k0 + 64 + i * 8);
#pragma unroll
      for (int i = 0; i < 4; i++) pb[i] = *(const uint4*)(sb0 + k0 + 64 + i * 8);
    }
#pragma unroll
    for (int kk = 0; kk < 2; kk++) {
      bf16x8 af[4], bfr[4];
#pragma unroll
      for (int mi = 0; mi < 4; mi++)
        af[mi] = *(const bf16x8*)&As[p][(wm * 64 + mi * 16 + l16) * 72 + kk * 32 + lhi * 8];
#pragma unroll
      for (int ni = 0; ni < 4; ni++)
        bfr[ni] = *(const bf16x8*)&Bs[p][(wn * 64 + ni * 16 + l16) * 72 + kk * 32 + lhi * 8];
#pragma unroll
      for (int mi = 0; mi < 4; mi++)
#pragma unroll
        for (int ni = 0; ni < 4; ni++)
          acc[mi][ni] = __builtin_amdgcn_mfma_f32_16x16x32_bf16(af[mi], bfr[ni], acc[mi][ni], 0, 0, 0);
    }
    if (more) {
      uint4* da = (uint4*)&As[p ^ 1][row * 72 + half * 32];
      uint4* db = (uint4*)&Bs[p ^ 1][row * 72 + half * 32];
#pragma unroll
      for (int i = 0; i < 4; i++) da[i] = pa[i];
#pragma unroll
      for (int i = 0; i < 4; i++) db[i] = pb[i];
    }
    __syncthreads();
    p ^= 1;
  }

#pragma unroll
  for (int mi = 0; mi < 4; mi++) {
#pragma unroll
    for (int r = 0; r < 4; r++) {
      const int grow = m0 + wm * 64 + mi * 16 + lhi * 4 + r;
#pragma unroll
      for (int ni = 0; ni < 4; ni++) {
        const int gcol = n0 + wn * 64 + ni * 16 + l16;
        size_t idx2 = (size_t)grow * EE + gcol;
        out[idx2] = acc[mi][ni][r] + x[idx2];
      }
    }
  }
}

// ---------------- launch ----------------------------------------------------
extern "C" void kernel_launch(void* const* d_in, const int* in_sizes, int n_in,
                              void* d_out, int out_size, void* d_ws, size_t ws_size,
                              hipStream_t stream) {
  const float* x  = (const float*)d_in[0];
  const float* Wq = (const float*)d_in[1];
  const float* Wk = (const float*)d_in[2];
  const float* Wv = (const float*)d_in[3];
  const float* Wm = (const float*)d_in[4];
  float* out = (float*)d_out;

  char* ws = (char*)d_ws;
  // layout (bytes):
  //   0        Q  f32 [64][2048]                (512 KB)
  //   524288   K  f32 [64][2048]                (512 KB)
  //   1048576  xnb bf16 [16384][512]            (16 MB)
  //   17825792 hr  bf16 [16384][512]            (16 MB)
  //   34603008 Mpart f32 [64][8][24][64]        (3.15 MB)
  //   37748736 mpart f32 [64][8][24]            (48 KB)
  //   37847040 Wvmt bf16 [512][512]             (512 KB)
  //   38371328 Mfull f32 [64][24][64]           (384 KB)
  //   38764544 mfull f32 [64][24]               (6 KB)
  float*  Qp    = (float*)(ws);
  float*  Kp    = (float*)(ws + 524288);
  ushort* xnb   = (ushort*)(ws + 1048576);
  ushort* hrp   = (ushort*)(ws + 17825792);
  float*  Mpart = (float*)(ws + 34603008);
  float*  mpart = (float*)(ws + 37748736);
  ushort* Wvmt  = (ushort*)(ws + 37847040);
  float*  Mfull = (float*)(ws + 38371328);
  float*  mfull = (float*)(ws + 38764544);

  k_ln<<<4096, 256, 0, stream>>>(x, Wq, Wk, Qp, Kp, xnb);
  k_wvm<<<EE, 256, 0, stream>>>(Wv, Wm, Wvmt);
  k_mom<<<512, 256, 0, stream>>>(Kp, xnb, Mpart, mpart);
  k_cmb<<<64, 256, 0, stream>>>(Mpart, mpart, Mfull, mfull);
  k_att2<<<1024, 256, 0, stream>>>(Qp, Mfull, mfull, hrp);
  k_merge<<<dim3(EE / 128, (8 * TT) / 128), 256, 0, stream>>>(hrp, Wvmt, x, out);
}